// Round 1
// baseline (374.227 us; speedup 1.0000x reference)
//
#include <hip/hip_runtime.h>

#define NN 10000    // nodes
#define RR 100      // relations
#define EE 5000     // edges per relation
#define D0 2048
#define D1 128
#define D2 64
#define D3 20
#define NE (RR*EE)  // 500000 edges total

using short8  = __attribute__((ext_vector_type(8))) short;
using float4e = __attribute__((ext_vector_type(4))) float;

__device__ __forceinline__ unsigned short f2bf(float f) {
  unsigned int u = __float_as_uint(f);
  unsigned int r = u + 0x7fffu + ((u >> 16) & 1u);   // RNE
  return (unsigned short)(r >> 16);
}
__device__ __forceinline__ float bf2f(unsigned short u) {
  return __uint_as_float(((unsigned int)u) << 16);
}
__device__ __forceinline__ unsigned int pk2(float lo, float hi) {
  return ((unsigned int)f2bf(hi) << 16) | (unsigned int)f2bf(lo);
}

// bf16x8 MFMA on uint4-typed fragments
__device__ __forceinline__ float4e bmm(uint4 a, uint4 b, float4e c) {
  return __builtin_amdgcn_mfma_f32_16x16x32_bf16(
      __builtin_bit_cast(short8, a), __builtin_bit_cast(short8, b), c, 0, 0, 0);
}
// pack 8 fp32 -> 8 bf16 fragment
__device__ __forceinline__ uint4 cvt8(float4 lo, float4 hi) {
  uint4 p;
  p.x = pk2(lo.x, lo.y); p.y = pk2(lo.z, lo.w);
  p.z = pk2(hi.x, hi.y); p.w = pk2(hi.z, hi.w);
  return p;
}

// ---------------------------------------------------------------------------
// CSR build (unchanged)
// ---------------------------------------------------------------------------
__global__ void deg_kernel(const int* __restrict__ ei, int* __restrict__ deg) {
  int gid = blockIdx.x * 256 + threadIdx.x;
  if (gid >= NE) return;
  int r = gid / EE, e = gid - r * EE;
  int d = ei[r * 2 * EE + EE + e];
  atomicAdd(&deg[r * NN + d], 1);
}

__global__ void cnt_kernel(const int* __restrict__ deg, int* __restrict__ cnt) {
  int n = blockIdx.x * 256 + threadIdx.x;
  if (n >= NN) return;
  int s = 0;
  for (int r = 0; r < RR; r++) s += deg[r * NN + n];
  cnt[n] = s;
}

__global__ __launch_bounds__(1024) void scan_kernel(const int* __restrict__ cnt,
                                                    int* __restrict__ off,
                                                    int* __restrict__ cur) {
  __shared__ int wsum[16];
  __shared__ int carry_s;
  const int tid = threadIdx.x;
  const int wv = tid >> 6, lane = tid & 63;
  if (tid == 0) carry_s = 0;
  __syncthreads();
  for (int base = 0; base < NN; base += 1024) {
    int i = base + tid;
    int v = (i < NN) ? cnt[i] : 0;
    int s = v;
#pragma unroll
    for (int d = 1; d < 64; d <<= 1) {
      int t = __shfl_up(s, d, 64);
      if (lane >= d) s += t;
    }
    if (lane == 63) wsum[wv] = s;
    __syncthreads();
    if (wv == 0) {
      int w = (lane < 16) ? wsum[lane] : 0;
#pragma unroll
      for (int d = 1; d < 16; d <<= 1) {
        int t = __shfl_up(w, d, 64);
        if (lane >= d) w += t;
      }
      if (lane < 16) wsum[lane] = w;
    }
    __syncthreads();
    int excl = carry_s + (wv > 0 ? wsum[wv - 1] : 0) + s - v;
    if (i < NN) { off[i] = excl; cur[i] = excl; }
    __syncthreads();
    if (tid == 1023) carry_s += wsum[15];
    __syncthreads();
  }
  if (tid == 0) off[NN] = carry_s;
}

// rec = (r<<14)|src, esc = 1/max(deg,1)
__global__ void scatter_kernel(const int* __restrict__ ei,
                               const int* __restrict__ deg,
                               int* __restrict__ cur, int* __restrict__ rec,
                               float* __restrict__ esc) {
  int gid = blockIdx.x * 256 + threadIdx.x;
  if (gid >= NE) return;
  int r = gid / EE, e = gid - r * EE;
  int s = ei[r * 2 * EE + e];
  int d = ei[r * 2 * EE + EE + e];
  int p = atomicAdd(&cur[d], 1);
  rec[p] = (r << 14) | s;
  esc[p] = 1.0f / fmaxf((float)deg[r * NN + d], 1.0f);
}

// ---------------------------------------------------------------------------
// weight prep (bf16, transposed [n][k] for MFMA B-frag loads) (unchanged)
// ---------------------------------------------------------------------------
__global__ void wtrans_kernel(const float* __restrict__ W,
                              unsigned short* __restrict__ Bt) {
  int idx = blockIdx.x * 256 + threadIdx.x;
  if (idx >= 128 * 2048) return;
  int n = idx >> 11, k = idx & 2047;
  Bt[idx] = f2bf(W[(size_t)k * 128 + n]);
}

__global__ void wc1t_kernel(const float* __restrict__ root1,
                            const float* __restrict__ basis1,
                            unsigned short* __restrict__ Wt) {
  int idx = blockIdx.x * 256 + threadIdx.x;
  if (idx >= 64 * 1152) return;
  int o = idx / 1152, j = idx - o * 1152;
  float v = (j < 128) ? root1[j * 64 + o] : basis1[(j - 128) * 64 + o];
  Wt[idx] = f2bf(v);
}

__global__ void wc2t_kernel(const float* __restrict__ root2,
                            const float* __restrict__ basis2,
                            unsigned short* __restrict__ Wt) {
  int idx = blockIdx.x * 256 + threadIdx.x;
  if (idx >= 32 * 576) return;
  int c = idx / 576, j = idx - c * 576;
  float v = 0.f;
  if (c < 20) v = (j < 64) ? root2[j * 20 + c] : basis2[(j - 64) * 20 + c];
  Wt[idx] = f2bf(v);
}

// ---------------------------------------------------------------------------
// gemm0_stream: xb = bf16(x_drug @ drug_w)
// No LDS, no barriers, no K-split. 625 blocks (M=16 each, exact), 4 waves;
// wave nw owns N-cols [nw*32, nw*32+32), full K=2048 (64 MFMA K-steps).
// A-frag loaded per-lane directly from global fp32 (lane = row l&15,
// k = quad*8..+8), converted in-register; B-frag from L2-resident bf16 Btw.
// Register double-buffer, prefetch distance 1 step.
// ---------------------------------------------------------------------------
__global__ __launch_bounds__(256) void gemm0_stream(
    const float* __restrict__ A, const unsigned short* __restrict__ Btw,
    unsigned short* __restrict__ xb) {
  const int tid = threadIdx.x;
  const int nw = tid >> 6, lane = tid & 63;
  const int lrow = lane & 15, quad = lane >> 4;
  const int m0 = blockIdx.x * 16;
  const int row = m0 + lrow;                      // 625*16 == 10000, no guard

  const float* ap = &A[(size_t)row * D0 + quad * 8];
  const unsigned short* bp0 = &Btw[(size_t)(nw * 32 + lrow) * D0 + quad * 8];
  const unsigned short* bp1 = bp0 + (size_t)16 * D0;

  float4 a0l, a0h, a1l, a1h;
  uint4  b0x, b0y, b1x, b1y;

#define G_LA0(c) { a0l = *(const float4*)(ap + (c) * 32); \
                   a0h = *(const float4*)(ap + (c) * 32 + 4); }
#define G_LA1(c) { a1l = *(const float4*)(ap + (c) * 32); \
                   a1h = *(const float4*)(ap + (c) * 32 + 4); }
#define G_LB0(c) { b0x = *(const uint4*)(bp0 + (c) * 32); \
                   b0y = *(const uint4*)(bp1 + (c) * 32); }
#define G_LB1(c) { b1x = *(const uint4*)(bp0 + (c) * 32); \
                   b1y = *(const uint4*)(bp1 + (c) * 32); }
#define G_C0() { uint4 af = cvt8(a0l, a0h); \
                 acc0 = bmm(af, b0x, acc0); acc1 = bmm(af, b0y, acc1); }
#define G_C1() { uint4 af = cvt8(a1l, a1h); \
                 acc0 = bmm(af, b1x, acc0); acc1 = bmm(af, b1y, acc1); }

  float4e acc0 = {0.f, 0.f, 0.f, 0.f};
  float4e acc1 = {0.f, 0.f, 0.f, 0.f};

  G_LA0(0); G_LB0(0);
  G_LA1(1); G_LB1(1);
  for (int c = 0; c <= 60; c += 2) {              // computes steps 0..61
    G_C0();
    G_LA0(c + 2); G_LB0(c + 2);                   // loads up to step 62
    G_C1();
    G_LA1(c + 3); G_LB1(c + 3);                   // loads up to step 63
  }
  G_C0();                                         // step 62
  G_C1();                                         // step 63

  const int c0 = nw * 32 + lrow;
#pragma unroll
  for (int j = 0; j < 4; j++) {
    int r = m0 + quad * 4 + j;
    xb[(size_t)r * D1 + c0]      = f2bf(acc0[j]);
    xb[(size_t)r * D1 + c0 + 16] = f2bf(acc1[j]);
  }
#undef G_LA0
#undef G_LA1
#undef G_LB0
#undef G_LB1
#undef G_C0
#undef G_C1
}

// ---------------------------------------------------------------------------
// agg1e: A1b[n, b*128+i] = bf16( sum_{e->n} esc_e*comp1[r_e,b]*x[src_e,i] )
// (unchanged)
// ---------------------------------------------------------------------------
__global__ __launch_bounds__(256) void agg1e_kernel(
    const unsigned short* __restrict__ xb, const int* __restrict__ off,
    const int* __restrict__ rec, const float* __restrict__ esc,
    const float* __restrict__ comp, unsigned short* __restrict__ A1b) {
  __shared__ float s_comp[RR * 8];
  const int tid = threadIdx.x;
  for (int i = tid; i < RR * 8; i += 256) s_comp[i] = comp[i];
  __syncthreads();
  const int wv = tid >> 6, lane = tid & 63;
  const int n = blockIdx.x * 4 + wv;
  if (n >= NN) return;
  float acc[8][2];
#pragma unroll
  for (int b = 0; b < 8; b++) { acc[b][0] = 0.f; acc[b][1] = 0.f; }
  const int beg = off[n], end = off[n + 1];
  int idx = beg;
  for (; idx + 3 < end; idx += 4) {
    int rc[4]; float sc[4]; unsigned int xv[4];
#pragma unroll
    for (int u = 0; u < 4; u++) {
      rc[u] = rec[idx + u];
      sc[u] = esc[idx + u];
    }
#pragma unroll
    for (int u = 0; u < 4; u++)
      xv[u] = *(const unsigned int*)&xb[(size_t)(rc[u] & 16383) * D1 + lane * 2];
#pragma unroll
    for (int u = 0; u < 4; u++) {
      const float* cb = &s_comp[(rc[u] >> 14) * 8];
      float x0 = __uint_as_float((xv[u] & 0xffffu) << 16);
      float x1 = __uint_as_float(xv[u] & 0xffff0000u);
#pragma unroll
      for (int b = 0; b < 8; b++) {
        float w = sc[u] * cb[b];
        acc[b][0] += w * x0;
        acc[b][1] += w * x1;
      }
    }
  }
  for (; idx < end; idx++) {
    int rc = rec[idx];
    float sc = esc[idx];
    unsigned int xv = *(const unsigned int*)&xb[(size_t)(rc & 16383) * D1 + lane * 2];
    const float* cb = &s_comp[(rc >> 14) * 8];
    float x0 = __uint_as_float((xv & 0xffffu) << 16);
    float x1 = __uint_as_float(xv & 0xffff0000u);
#pragma unroll
    for (int b = 0; b < 8; b++) {
      float w = sc * cb[b];
      acc[b][0] += w * x0;
      acc[b][1] += w * x1;
    }
  }
#pragma unroll
  for (int b = 0; b < 8; b++) {
    ushort2 o; o.x = f2bf(acc[b][0]); o.y = f2bf(acc[b][1]);
    *(ushort2*)&A1b[(size_t)n * 1024 + b * 128 + lane * 2] = o;
  }
}

// ---------------------------------------------------------------------------
// agg2e (unchanged)
// ---------------------------------------------------------------------------
__global__ __launch_bounds__(256) void agg2e_kernel(
    const unsigned short* __restrict__ hb, const int* __restrict__ off,
    const int* __restrict__ rec, const float* __restrict__ esc,
    const float* __restrict__ comp, unsigned short* __restrict__ A2b) {
  __shared__ float s_comp[RR * 8];
  const int tid = threadIdx.x;
  for (int i = tid; i < RR * 8; i += 256) s_comp[i] = comp[i];
  __syncthreads();
  const int wv = tid >> 6, lane = tid & 63;
  const int n = blockIdx.x * 4 + wv;
  if (n >= NN) return;
  float acc[8];
#pragma unroll
  for (int b = 0; b < 8; b++) acc[b] = 0.f;
  const int beg = off[n], end = off[n + 1];
  int idx = beg;
  for (; idx + 3 < end; idx += 4) {
    int rc[4]; float sc[4]; float hv[4];
#pragma unroll
    for (int u = 0; u < 4; u++) {
      rc[u] = rec[idx + u];
      sc[u] = esc[idx + u];
    }
#pragma unroll
    for (int u = 0; u < 4; u++)
      hv[u] = bf2f(hb[(size_t)(rc[u] & 16383) * D2 + lane]);
#pragma unroll
    for (int u = 0; u < 4; u++) {
      const float* cb = &s_comp[(rc[u] >> 14) * 8];
#pragma unroll
      for (int b = 0; b < 8; b++) acc[b] += sc[u] * cb[b] * hv[u];
    }
  }
  for (; idx < end; idx++) {
    int rc = rec[idx];
    float sc = esc[idx];
    float hv = bf2f(hb[(size_t)(rc & 16383) * D2 + lane]);
    const float* cb = &s_comp[(rc >> 14) * 8];
#pragma unroll
    for (int b = 0; b < 8; b++) acc[b] += sc * cb[b] * hv;
  }
#pragma unroll
  for (int b = 0; b < 8; b++)
    A2b[(size_t)n * 512 + b * 64 + lane] = f2bf(acc[b]);
}

// ---------------------------------------------------------------------------
// hlayer_stream: hb = bf16(relu([xb|A1b](K=1152) @ Wc1T + bias1))
// No LDS/barriers. 625 blocks (M=16), 4 waves; wave nt owns one 16-col tile.
// A already bf16 -> per-lane uint4 frag loads straight from xb/A1b;
// B-frags from L2-resident Wc1T. Register double-buffer, 36 K-steps.
// ---------------------------------------------------------------------------
__global__ __launch_bounds__(256) void hlayer_stream(
    const unsigned short* __restrict__ xb, const unsigned short* __restrict__ A1b,
    const unsigned short* __restrict__ Wt, const float* __restrict__ bias1,
    unsigned short* __restrict__ hb) {
  const int tid = threadIdx.x;
  const int nt = tid >> 6, lane = tid & 63;
  const int lrow = lane & 15, quad = lane >> 4;
  const int m0 = blockIdx.x * 16;
  const int row = m0 + lrow;

  const unsigned short* ax = &xb[(size_t)row * D1 + quad * 8];
  const unsigned short* aa = &A1b[(size_t)row * 1024 + quad * 8];
  const unsigned short* bp = &Wt[(size_t)(nt * 16 + lrow) * 1152 + quad * 8];

#define H_LA(k) (((k) < 128) ? *(const uint4*)(ax + (k)) \
                             : *(const uint4*)(aa + ((k) - 128)))

  uint4 A0 = H_LA(0),  B0 = *(const uint4*)(bp);
  uint4 A1 = H_LA(32), B1 = *(const uint4*)(bp + 32);
  float4e acc = {0.f, 0.f, 0.f, 0.f};

  for (int c = 0; c <= 32; c += 2) {              // computes steps 0..33
    acc = bmm(A0, B0, acc);
    { int k = (c + 2) * 32; A0 = H_LA(k); B0 = *(const uint4*)(bp + k); }
    acc = bmm(A1, B1, acc);
    { int k = (c + 3) * 32; A1 = H_LA(k); B1 = *(const uint4*)(bp + k); }
  }
  acc = bmm(A0, B0, acc);                         // step 34
  acc = bmm(A1, B1, acc);                         // step 35
#undef H_LA

  const int col = nt * 16 + lrow;
  const float bv = bias1[col];
#pragma unroll
  for (int j = 0; j < 4; j++) {
    int r = m0 + quad * 4 + j;
    hb[(size_t)r * D2 + col] = f2bf(fmaxf(acc[j] + bv, 0.f));
  }
}

// ---------------------------------------------------------------------------
// out_stream: out = [hb|A2b](K=576) @ Wc2T + bias2
// 625 blocks (M=16), 2 waves (128 thr); wave nt owns one 16-col tile
// (cols 20..31 are zero-padded in Wc2T and discarded). 18 K-steps.
// ---------------------------------------------------------------------------
__global__ __launch_bounds__(128) void out_stream(
    const unsigned short* __restrict__ hb, const unsigned short* __restrict__ A2b,
    const unsigned short* __restrict__ Wt, const float* __restrict__ bias2,
    float* __restrict__ out) {
  const int tid = threadIdx.x;
  const int nt = tid >> 6, lane = tid & 63;
  const int lrow = lane & 15, quad = lane >> 4;
  const int m0 = blockIdx.x * 16;
  const int row = m0 + lrow;

  const unsigned short* ah = &hb[(size_t)row * D2 + quad * 8];
  const unsigned short* aa = &A2b[(size_t)row * 512 + quad * 8];
  const unsigned short* bp = &Wt[(size_t)(nt * 16 + lrow) * 576 + quad * 8];

#define O_LA(k) (((k) < 64) ? *(const uint4*)(ah + (k)) \
                            : *(const uint4*)(aa + ((k) - 64)))

  uint4 A0 = O_LA(0),  B0 = *(const uint4*)(bp);
  uint4 A1 = O_LA(32), B1 = *(const uint4*)(bp + 32);
  float4e acc = {0.f, 0.f, 0.f, 0.f};

  for (int c = 0; c <= 14; c += 2) {              // computes steps 0..15
    acc = bmm(A0, B0, acc);
    { int k = (c + 2) * 32; A0 = O_LA(k); B0 = *(const uint4*)(bp + k); }
    acc = bmm(A1, B1, acc);
    { int k = (c + 3) * 32; A1 = O_LA(k); B1 = *(const uint4*)(bp + k); }
  }
  acc = bmm(A0, B0, acc);                         // step 16
  acc = bmm(A1, B1, acc);                         // step 17
#undef O_LA

  const int col = nt * 16 + lrow;
  if (col < D3) {
    const float bv = bias2[col];
#pragma unroll
    for (int j = 0; j < 4; j++) {
      int r = m0 + quad * 4 + j;
      out[(size_t)r * D3 + col] = acc[j] + bv;
    }
  }
}

// ---------------------------------------------------------------------------
extern "C" void kernel_launch(void* const* d_in, const int* in_sizes, int n_in,
                              void* d_out, int out_size, void* d_ws,
                              size_t ws_size, hipStream_t stream) {
  const float* x_drug = (const float*)d_in[0];
  const float* drug_w = (const float*)d_in[1];
  const int*   ei     = (const int*)d_in[2];
  const float* basis1 = (const float*)d_in[3];
  const float* comp1  = (const float*)d_in[4];
  const float* root1  = (const float*)d_in[5];
  const float* bias1  = (const float*)d_in[6];
  const float* basis2 = (const float*)d_in[7];
  const float* comp2  = (const float*)d_in[8];
  const float* root2  = (const float*)d_in[9];
  const float* bias2  = (const float*)d_in[10];
  float* out = (float*)d_out;

  float* ws = (float*)d_ws;
  int*   deg  = (int*)ws;                          // 1,000,000
  int*   cnt  = deg + 1000000;                     // 10,016
  int*   off  = cnt + 10016;                       // 10,016
  int*   cur  = off + 10016;                       // 10,016
  int*   rec  = cur + 10016;                       // 500,000
  float* esc  = (float*)(rec + 500000);            // 500,000
  unsigned short* xb   = (unsigned short*)(esc + 500000);          // 640,000 f
  unsigned short* hb   = (unsigned short*)((float*)xb + 640000);   // 320,000 f
  unsigned short* Btw  = (unsigned short*)((float*)hb + 320000);   // 131,072 f
  unsigned short* Wc1T = (unsigned short*)((float*)Btw + 131072);  // 36,864 f
  unsigned short* Wc2T = (unsigned short*)((float*)Wc1T + 36864);  // 9,216 f
  float* R1 = (float*)Wc2T + 9216;                 // aggregation buffers
  unsigned short* A1b = (unsigned short*)R1;       // 10,000 x 1024 bf16
  unsigned short* A2b = (unsigned short*)R1;       // aliases A1b (after hlayer)

  hipMemsetAsync(deg, 0, (size_t)1000000 * 4, stream);

  // CSR build
  deg_kernel<<<(NE + 255) / 256, 256, 0, stream>>>(ei, deg);
  cnt_kernel<<<(NN + 255) / 256, 256, 0, stream>>>(deg, cnt);
  scan_kernel<<<1, 1024, 0, stream>>>(cnt, off, cur);
  scatter_kernel<<<(NE + 255) / 256, 256, 0, stream>>>(ei, deg, cur, rec, esc);

  // weights
  wtrans_kernel<<<(128 * 2048 + 255) / 256, 256, 0, stream>>>(drug_w, Btw);
  wc1t_kernel<<<(64 * 1152 + 255) / 256, 256, 0, stream>>>(root1, basis1, Wc1T);
  wc2t_kernel<<<(32 * 576 + 255) / 256, 256, 0, stream>>>(root2, basis2, Wc2T);

  // x = x_drug @ drug_w  (streaming bf16 MFMA, full K, no partials)
  gemm0_stream<<<NN / 16, 256, 0, stream>>>(x_drug, Btw, xb);

  // layer 1
  agg1e_kernel<<<(NN + 3) / 4, 256, 0, stream>>>(xb, off, rec, esc, comp1, A1b);
  hlayer_stream<<<NN / 16, 256, 0, stream>>>(xb, A1b, Wc1T, bias1, hb);

  // layer 2
  agg2e_kernel<<<(NN + 3) / 4, 256, 0, stream>>>(hb, off, rec, esc, comp2, A2b);
  out_stream<<<NN / 16, 128, 0, stream>>>(hb, A2b, Wc2T, bias2, out);
}

// Round 2
// 322.159 us; speedup vs baseline: 1.1616x; 1.1616x over previous
//
#include <hip/hip_runtime.h>

#define NN 10000    // nodes
#define RR 100      // relations
#define EE 5000     // edges per relation
#define D0 2048
#define D1 128
#define D2 64
#define D3 20
#define NE (RR*EE)  // 500000 edges total

using short8  = __attribute__((ext_vector_type(8))) short;
using float4e = __attribute__((ext_vector_type(4))) float;

__device__ __forceinline__ unsigned short f2bf(float f) {
  unsigned int u = __float_as_uint(f);
  unsigned int r = u + 0x7fffu + ((u >> 16) & 1u);   // RNE
  return (unsigned short)(r >> 16);
}
__device__ __forceinline__ float bf2f(unsigned short u) {
  return __uint_as_float(((unsigned int)u) << 16);
}
__device__ __forceinline__ unsigned int pk2(float lo, float hi) {
  return ((unsigned int)f2bf(hi) << 16) | (unsigned int)f2bf(lo);
}

// bf16x8 MFMA on uint4-typed fragments
__device__ __forceinline__ float4e bmm(uint4 a, uint4 b, float4e c) {
  return __builtin_amdgcn_mfma_f32_16x16x32_bf16(
      __builtin_bit_cast(short8, a), __builtin_bit_cast(short8, b), c, 0, 0, 0);
}

// ---------------------------------------------------------------------------
// CSR build (unchanged)
// ---------------------------------------------------------------------------
__global__ void deg_kernel(const int* __restrict__ ei, int* __restrict__ deg) {
  int gid = blockIdx.x * 256 + threadIdx.x;
  if (gid >= NE) return;
  int r = gid / EE, e = gid - r * EE;
  int d = ei[r * 2 * EE + EE + e];
  atomicAdd(&deg[r * NN + d], 1);
}

__global__ void cnt_kernel(const int* __restrict__ deg, int* __restrict__ cnt) {
  int n = blockIdx.x * 256 + threadIdx.x;
  if (n >= NN) return;
  int s = 0;
  for (int r = 0; r < RR; r++) s += deg[r * NN + n];
  cnt[n] = s;
}

__global__ __launch_bounds__(1024) void scan_kernel(const int* __restrict__ cnt,
                                                    int* __restrict__ off,
                                                    int* __restrict__ cur) {
  __shared__ int wsum[16];
  __shared__ int carry_s;
  const int tid = threadIdx.x;
  const int wv = tid >> 6, lane = tid & 63;
  if (tid == 0) carry_s = 0;
  __syncthreads();
  for (int base = 0; base < NN; base += 1024) {
    int i = base + tid;
    int v = (i < NN) ? cnt[i] : 0;
    int s = v;
#pragma unroll
    for (int d = 1; d < 64; d <<= 1) {
      int t = __shfl_up(s, d, 64);
      if (lane >= d) s += t;
    }
    if (lane == 63) wsum[wv] = s;
    __syncthreads();
    if (wv == 0) {
      int w = (lane < 16) ? wsum[lane] : 0;
#pragma unroll
      for (int d = 1; d < 16; d <<= 1) {
        int t = __shfl_up(w, d, 64);
        if (lane >= d) w += t;
      }
      if (lane < 16) wsum[lane] = w;
    }
    __syncthreads();
    int excl = carry_s + (wv > 0 ? wsum[wv - 1] : 0) + s - v;
    if (i < NN) { off[i] = excl; cur[i] = excl; }
    __syncthreads();
    if (tid == 1023) carry_s += wsum[15];
    __syncthreads();
  }
  if (tid == 0) off[NN] = carry_s;
}

// rec = (r<<14)|src, esc = 1/max(deg,1)
__global__ void scatter_kernel(const int* __restrict__ ei,
                               const int* __restrict__ deg,
                               int* __restrict__ cur, int* __restrict__ rec,
                               float* __restrict__ esc) {
  int gid = blockIdx.x * 256 + threadIdx.x;
  if (gid >= NE) return;
  int r = gid / EE, e = gid - r * EE;
  int s = ei[r * 2 * EE + e];
  int d = ei[r * 2 * EE + EE + e];
  int p = atomicAdd(&cur[d], 1);
  rec[p] = (r << 14) | s;
  esc[p] = 1.0f / fmaxf((float)deg[r * NN + d], 1.0f);
}

// ---------------------------------------------------------------------------
// weight prep: bf16, MFMA-FRAGMENT order  [kstep][ntile][lane][8]
// so a wave's B-frag load is one coalesced 1 KB read (base + lane*16B).
// frag element: k = c*32 + (lane>>4)*8 + j, n = nt*16 + (lane&15)
// ---------------------------------------------------------------------------
__global__ void wtrans_kernel(const float* __restrict__ W,
                              unsigned short* __restrict__ Bf) {
  int idx = blockIdx.x * 256 + threadIdx.x;       // 64*8*64*8 = 262144
  if (idx >= 262144) return;
  int j = idx & 7, lane = (idx >> 3) & 63, rest = idx >> 9;
  int nt = rest & 7, c = rest >> 3;               // nt 0..7, c 0..63
  int k = c * 32 + (lane >> 4) * 8 + j;
  int n = nt * 16 + (lane & 15);
  Bf[idx] = f2bf(W[(size_t)k * 128 + n]);
}

__global__ void wc1t_kernel(const float* __restrict__ root1,
                            const float* __restrict__ basis1,
                            unsigned short* __restrict__ Wf) {
  int idx = blockIdx.x * 256 + threadIdx.x;       // 36*4*64*8 = 73728
  if (idx >= 73728) return;
  int j = idx & 7, lane = (idx >> 3) & 63, rest = idx >> 9;
  int nt = rest & 3, c = rest >> 2;               // nt 0..3, c 0..35
  int k = c * 32 + (lane >> 4) * 8 + j;
  int o = nt * 16 + (lane & 15);
  float v = (k < 128) ? root1[k * 64 + o] : basis1[(k - 128) * 64 + o];
  Wf[idx] = f2bf(v);
}

__global__ void wc2t_kernel(const float* __restrict__ root2,
                            const float* __restrict__ basis2,
                            unsigned short* __restrict__ Wf) {
  int idx = blockIdx.x * 256 + threadIdx.x;       // 18*2*64*8 = 18432
  if (idx >= 18432) return;
  int j = idx & 7, lane = (idx >> 3) & 63, rest = idx >> 9;
  int nt = rest & 1, c = rest >> 1;               // nt 0..1, c 0..17
  int k = c * 32 + (lane >> 4) * 8 + j;
  int cc = nt * 16 + (lane & 15);
  float v = 0.f;
  if (cc < 20) v = (k < 64) ? root2[k * 20 + cc] : basis2[(k - 64) * 20 + cc];
  Wf[idx] = f2bf(v);
}

// ---------------------------------------------------------------------------
// gemm0_v3: xb = bf16(x_drug @ drug_w)
// 625 blocks (M=16), 4 waves (wave nw owns cols nw*32..+32), K=2048.
// A: coalesced-staged into double-buffered 4 KB bf16 LDS tile [16][128],
//    XOR-swizzled 16B slots (read = 2-way conflict = free); fp32->bf16
//    conversion in registers before ds_write; A prefetched 2 tiles ahead.
// B: pre-arranged fragment layout -> coalesced 1 KB loads, 1 tile ahead.
// 1 barrier per K-tile (16 total); loads stay in flight across it.
// ---------------------------------------------------------------------------
__global__ __launch_bounds__(256) void gemm0_v3(
    const float* __restrict__ A, const unsigned short* __restrict__ Bfw,
    unsigned short* __restrict__ xb) {
  __shared__ unsigned short As[2][16 * 128];
  const int tid = threadIdx.x;
  const int nw = tid >> 6, lane = tid & 63;
  const int lrow = lane & 15, quad = lane >> 4;
  const int m0 = blockIdx.x * 16;

  // staging: thread covers rows srow and srow+8, 4 fp32 each (coalesced 512B/row)
  const int srow = tid >> 5;                       // 0..7
  const float* ap0 = &A[(size_t)(m0 + srow) * D0 + (tid & 31) * 4];
  const float* ap1 = ap0 + (size_t)8 * D0;
  // swizzled LDS write offsets (bf16 units): phys(r,s) = r*128 + ((s^r)&15)*8
  const int wslot = (tid & 31) >> 1;
  const int wo0 = srow * 128 + ((wslot ^ srow) & 15) * 8 + (tid & 1) * 4;
  const int wo1 = (srow + 8) * 128 + ((wslot ^ (srow + 8)) & 15) * 8 + (tid & 1) * 4;
  // frag read offsets: row lrow, logical slot kk*4+quad
  int ro[4];
#pragma unroll
  for (int kk = 0; kk < 4; kk++)
    ro[kk] = lrow * 128 + (((kk * 4 + quad) ^ lrow) & 15) * 8;

  const uint4* Bq = (const uint4*)Bfw;

  float4 rAe0, rAe1, rAo0, rAo1;                   // raw A, two tiles in flight
  uint4 B0[8], B1[8];                              // B frags, double-buffered
  float4e acc0 = {0.f, 0.f, 0.f, 0.f};
  float4e acc1 = {0.f, 0.f, 0.f, 0.f};

#define LDA(ra, rb, t)                                     \
  { int tc = (t) > 15 ? 15 : (t);                          \
    ra = *(const float4*)(ap0 + tc * 128);                 \
    rb = *(const float4*)(ap1 + tc * 128); }
#define LDB(B, t)                                          \
  { int tc = (t) > 15 ? 15 : (t);                          \
    _Pragma("unroll")                                      \
    for (int kk = 0; kk < 4; kk++) {                       \
      B[2 * kk]     = Bq[((tc * 4 + kk) * 8 + 2 * nw) * 64 + lane];     \
      B[2 * kk + 1] = Bq[((tc * 4 + kk) * 8 + 2 * nw + 1) * 64 + lane]; }}
#define STA(buf, ra, rb)                                   \
  { uint2 u0, u1;                                          \
    u0.x = pk2(ra.x, ra.y); u0.y = pk2(ra.z, ra.w);        \
    u1.x = pk2(rb.x, rb.y); u1.y = pk2(rb.z, rb.w);        \
    *(uint2*)&As[buf][wo0] = u0;                           \
    *(uint2*)&As[buf][wo1] = u1; }
#define CMP(buf, B)                                        \
  { _Pragma("unroll")                                      \
    for (int kk = 0; kk < 4; kk++) {                       \
      uint4 af = *(const uint4*)&As[buf][ro[kk]];          \
      acc0 = bmm(af, B[2 * kk], acc0);                     \
      acc1 = bmm(af, B[2 * kk + 1], acc1); } }

  // prologue: LDS0 = tile0; B0 = tile0; B1 = tile1; rAo = tile1; rAe = tile2
  LDA(rAe0, rAe1, 0);
  LDB(B0, 0);
  LDA(rAo0, rAo1, 1);
  STA(0, rAe0, rAe1);
  LDB(B1, 1);
  LDA(rAe0, rAe1, 2);
  __syncthreads();

  for (int t = 0; t < 16; t += 2) {
    // even tile t: compute LDS0/B0, stage tile t+1 into LDS1
    STA(1, rAo0, rAo1);
    LDA(rAo0, rAo1, t + 3);
    CMP(0, B0);
    LDB(B0, t + 2);
    __syncthreads();
    // odd tile t+1: compute LDS1/B1, stage tile t+2 into LDS0
    STA(0, rAe0, rAe1);
    LDA(rAe0, rAe1, t + 4);
    CMP(1, B1);
    LDB(B1, t + 3);
    __syncthreads();
  }
#undef LDA
#undef LDB
#undef STA
#undef CMP

  const int c0 = nw * 32 + lrow;
#pragma unroll
  for (int j = 0; j < 4; j++) {
    int r = m0 + quad * 4 + j;
    xb[(size_t)r * D1 + c0]      = f2bf(acc0[j]);
    xb[(size_t)r * D1 + c0 + 16] = f2bf(acc1[j]);
  }
}

// ---------------------------------------------------------------------------
// agg1e (unchanged)
// ---------------------------------------------------------------------------
__global__ __launch_bounds__(256) void agg1e_kernel(
    const unsigned short* __restrict__ xb, const int* __restrict__ off,
    const int* __restrict__ rec, const float* __restrict__ esc,
    const float* __restrict__ comp, unsigned short* __restrict__ A1b) {
  __shared__ float s_comp[RR * 8];
  const int tid = threadIdx.x;
  for (int i = tid; i < RR * 8; i += 256) s_comp[i] = comp[i];
  __syncthreads();
  const int wv = tid >> 6, lane = tid & 63;
  const int n = blockIdx.x * 4 + wv;
  if (n >= NN) return;
  float acc[8][2];
#pragma unroll
  for (int b = 0; b < 8; b++) { acc[b][0] = 0.f; acc[b][1] = 0.f; }
  const int beg = off[n], end = off[n + 1];
  int idx = beg;
  for (; idx + 3 < end; idx += 4) {
    int rc[4]; float sc[4]; unsigned int xv[4];
#pragma unroll
    for (int u = 0; u < 4; u++) {
      rc[u] = rec[idx + u];
      sc[u] = esc[idx + u];
    }
#pragma unroll
    for (int u = 0; u < 4; u++)
      xv[u] = *(const unsigned int*)&xb[(size_t)(rc[u] & 16383) * D1 + lane * 2];
#pragma unroll
    for (int u = 0; u < 4; u++) {
      const float* cb = &s_comp[(rc[u] >> 14) * 8];
      float x0 = __uint_as_float((xv[u] & 0xffffu) << 16);
      float x1 = __uint_as_float(xv[u] & 0xffff0000u);
#pragma unroll
      for (int b = 0; b < 8; b++) {
        float w = sc[u] * cb[b];
        acc[b][0] += w * x0;
        acc[b][1] += w * x1;
      }
    }
  }
  for (; idx < end; idx++) {
    int rc = rec[idx];
    float sc = esc[idx];
    unsigned int xv = *(const unsigned int*)&xb[(size_t)(rc & 16383) * D1 + lane * 2];
    const float* cb = &s_comp[(rc >> 14) * 8];
    float x0 = __uint_as_float((xv & 0xffffu) << 16);
    float x1 = __uint_as_float(xv & 0xffff0000u);
#pragma unroll
    for (int b = 0; b < 8; b++) {
      float w = sc * cb[b];
      acc[b][0] += w * x0;
      acc[b][1] += w * x1;
    }
  }
#pragma unroll
  for (int b = 0; b < 8; b++) {
    ushort2 o; o.x = f2bf(acc[b][0]); o.y = f2bf(acc[b][1]);
    *(ushort2*)&A1b[(size_t)n * 1024 + b * 128 + lane * 2] = o;
  }
}

// ---------------------------------------------------------------------------
// agg2e (unchanged)
// ---------------------------------------------------------------------------
__global__ __launch_bounds__(256) void agg2e_kernel(
    const unsigned short* __restrict__ hb, const int* __restrict__ off,
    const int* __restrict__ rec, const float* __restrict__ esc,
    const float* __restrict__ comp, unsigned short* __restrict__ A2b) {
  __shared__ float s_comp[RR * 8];
  const int tid = threadIdx.x;
  for (int i = tid; i < RR * 8; i += 256) s_comp[i] = comp[i];
  __syncthreads();
  const int wv = tid >> 6, lane = tid & 63;
  const int n = blockIdx.x * 4 + wv;
  if (n >= NN) return;
  float acc[8];
#pragma unroll
  for (int b = 0; b < 8; b++) acc[b] = 0.f;
  const int beg = off[n], end = off[n + 1];
  int idx = beg;
  for (; idx + 3 < end; idx += 4) {
    int rc[4]; float sc[4]; float hv[4];
#pragma unroll
    for (int u = 0; u < 4; u++) {
      rc[u] = rec[idx + u];
      sc[u] = esc[idx + u];
    }
#pragma unroll
    for (int u = 0; u < 4; u++)
      hv[u] = bf2f(hb[(size_t)(rc[u] & 16383) * D2 + lane]);
#pragma unroll
    for (int u = 0; u < 4; u++) {
      const float* cb = &s_comp[(rc[u] >> 14) * 8];
#pragma unroll
      for (int b = 0; b < 8; b++) acc[b] += sc[u] * cb[b] * hv[u];
    }
  }
  for (; idx < end; idx++) {
    int rc = rec[idx];
    float sc = esc[idx];
    float hv = bf2f(hb[(size_t)(rc & 16383) * D2 + lane]);
    const float* cb = &s_comp[(rc >> 14) * 8];
#pragma unroll
    for (int b = 0; b < 8; b++) acc[b] += sc * cb[b] * hv;
  }
#pragma unroll
  for (int b = 0; b < 8; b++)
    A2b[(size_t)n * 512 + b * 64 + lane] = f2bf(acc[b]);
}

// ---------------------------------------------------------------------------
// hlayer_stream: hb = bf16(relu([xb|A1b](K=1152) @ Wc1 + bias1))
// B now from fragment layout (coalesced); A per-lane from L2-resident xb/A1b.
// ---------------------------------------------------------------------------
__global__ __launch_bounds__(256) void hlayer_stream(
    const unsigned short* __restrict__ xb, const unsigned short* __restrict__ A1b,
    const unsigned short* __restrict__ Wf, const float* __restrict__ bias1,
    unsigned short* __restrict__ hb) {
  const int tid = threadIdx.x;
  const int nt = tid >> 6, lane = tid & 63;
  const int lrow = lane & 15, quad = lane >> 4;
  const int m0 = blockIdx.x * 16;
  const int row = m0 + lrow;

  const unsigned short* ax = &xb[(size_t)row * D1 + quad * 8];
  const unsigned short* aa = &A1b[(size_t)row * 1024 + quad * 8];

#define H_LA(k) (((k) < 128) ? *(const uint4*)(ax + (k)) \
                             : *(const uint4*)(aa + ((k) - 128)))
#define H_LB(c) (*(const uint4*)(Wf + (((size_t)(c) * 4 + nt) * 64 + lane) * 8))

  uint4 A0 = H_LA(0),  B0 = H_LB(0);
  uint4 A1 = H_LA(32), B1 = H_LB(1);
  float4e acc = {0.f, 0.f, 0.f, 0.f};

  for (int c = 0; c <= 32; c += 2) {              // computes steps 0..33
    acc = bmm(A0, B0, acc);
    { int k = (c + 2) * 32; A0 = H_LA(k); B0 = H_LB(c + 2); }
    acc = bmm(A1, B1, acc);
    { int k = (c + 3) * 32; A1 = H_LA(k); B1 = H_LB(c + 3); }
  }
  acc = bmm(A0, B0, acc);                         // step 34
  acc = bmm(A1, B1, acc);                         // step 35
#undef H_LA
#undef H_LB

  const int col = nt * 16 + lrow;
  const float bv = bias1[col];
#pragma unroll
  for (int j = 0; j < 4; j++) {
    int r = m0 + quad * 4 + j;
    hb[(size_t)r * D2 + col] = f2bf(fmaxf(acc[j] + bv, 0.f));
  }
}

// ---------------------------------------------------------------------------
// out_stream: out = [hb|A2b](K=576) @ Wc2 + bias2  (frag-layout B)
// ---------------------------------------------------------------------------
__global__ __launch_bounds__(128) void out_stream(
    const unsigned short* __restrict__ hb, const unsigned short* __restrict__ A2b,
    const unsigned short* __restrict__ Wf, const float* __restrict__ bias2,
    float* __restrict__ out) {
  const int tid = threadIdx.x;
  const int nt = tid >> 6, lane = tid & 63;
  const int lrow = lane & 15, quad = lane >> 4;
  const int m0 = blockIdx.x * 16;
  const int row = m0 + lrow;

  const unsigned short* ah = &hb[(size_t)row * D2 + quad * 8];
  const unsigned short* aa = &A2b[(size_t)row * 512 + quad * 8];

#define O_LA(k) (((k) < 64) ? *(const uint4*)(ah + (k)) \
                            : *(const uint4*)(aa + ((k) - 64)))
#define O_LB(c) (*(const uint4*)(Wf + (((size_t)(c) * 2 + nt) * 64 + lane) * 8))

  uint4 A0 = O_LA(0),  B0 = O_LB(0);
  uint4 A1 = O_LA(32), B1 = O_LB(1);
  float4e acc = {0.f, 0.f, 0.f, 0.f};

  for (int c = 0; c <= 14; c += 2) {              // computes steps 0..15
    acc = bmm(A0, B0, acc);
    { int k = (c + 2) * 32; A0 = O_LA(k); B0 = O_LB(c + 2); }
    acc = bmm(A1, B1, acc);
    { int k = (c + 3) * 32; A1 = O_LA(k); B1 = O_LB(c + 3); }
  }
  acc = bmm(A0, B0, acc);                         // step 16
  acc = bmm(A1, B1, acc);                         // step 17
#undef O_LA
#undef O_LB

  const int col = nt * 16 + lrow;
  if (col < D3) {
    const float bv = bias2[col];
#pragma unroll
    for (int j = 0; j < 4; j++) {
      int r = m0 + quad * 4 + j;
      out[(size_t)r * D3 + col] = acc[j] + bv;
    }
  }
}

// ---------------------------------------------------------------------------
extern "C" void kernel_launch(void* const* d_in, const int* in_sizes, int n_in,
                              void* d_out, int out_size, void* d_ws,
                              size_t ws_size, hipStream_t stream) {
  const float* x_drug = (const float*)d_in[0];
  const float* drug_w = (const float*)d_in[1];
  const int*   ei     = (const int*)d_in[2];
  const float* basis1 = (const float*)d_in[3];
  const float* comp1  = (const float*)d_in[4];
  const float* root1  = (const float*)d_in[5];
  const float* bias1  = (const float*)d_in[6];
  const float* basis2 = (const float*)d_in[7];
  const float* comp2  = (const float*)d_in[8];
  const float* root2  = (const float*)d_in[9];
  const float* bias2  = (const float*)d_in[10];
  float* out = (float*)d_out;

  float* ws = (float*)d_ws;
  int*   deg  = (int*)ws;                          // 1,000,000
  int*   cnt  = deg + 1000000;                     // 10,016
  int*   off  = cnt + 10016;                       // 10,016
  int*   cur  = off + 10016;                       // 10,016
  int*   rec  = cur + 10016;                       // 500,000
  float* esc  = (float*)(rec + 500000);            // 500,000
  unsigned short* xb   = (unsigned short*)(esc + 500000);          // 640,000 f
  unsigned short* hb   = (unsigned short*)((float*)xb + 640000);   // 320,000 f
  unsigned short* Bfw  = (unsigned short*)((float*)hb + 320000);   // 131,072 f
  unsigned short* Wf1  = (unsigned short*)((float*)Bfw + 131072);  // 36,864 f
  unsigned short* Wf2  = (unsigned short*)((float*)Wf1 + 36864);   // 9,216 f
  float* R1 = (float*)Wf2 + 9216;                  // aggregation buffers
  unsigned short* A1b = (unsigned short*)R1;       // 10,000 x 1024 bf16
  unsigned short* A2b = (unsigned short*)R1;       // aliases A1b (after hlayer)

  hipMemsetAsync(deg, 0, (size_t)1000000 * 4, stream);

  // CSR build
  deg_kernel<<<(NE + 255) / 256, 256, 0, stream>>>(ei, deg);
  cnt_kernel<<<(NN + 255) / 256, 256, 0, stream>>>(deg, cnt);
  scan_kernel<<<1, 1024, 0, stream>>>(cnt, off, cur);
  scatter_kernel<<<(NE + 255) / 256, 256, 0, stream>>>(ei, deg, cur, rec, esc);

  // weights (fragment layouts)
  wtrans_kernel<<<262144 / 256, 256, 0, stream>>>(drug_w, Bfw);
  wc1t_kernel<<<73728 / 256, 256, 0, stream>>>(root1, basis1, Wf1);
  wc2t_kernel<<<18432 / 256, 256, 0, stream>>>(root2, basis2, Wf2);

  // x = x_drug @ drug_w
  gemm0_v3<<<NN / 16, 256, 0, stream>>>(x_drug, Bfw, xb);

  // layer 1
  agg1e_kernel<<<(NN + 3) / 4, 256, 0, stream>>>(xb, off, rec, esc, comp1, A1b);
  hlayer_stream<<<NN / 16, 256, 0, stream>>>(xb, A1b, Wf1, bias1, hb);

  // layer 2
  agg2e_kernel<<<(NN + 3) / 4, 256, 0, stream>>>(hb, off, rec, esc, comp2, A2b);
  out_stream<<<NN / 16, 128, 0, stream>>>(hb, A2b, Wf2, bias2, out);
}

// Round 3
// 303.936 us; speedup vs baseline: 1.2313x; 1.0600x over previous
//
#include <hip/hip_runtime.h>

#define NN 10000    // nodes
#define RR 100      // relations
#define EE 5000     // edges per relation
#define D0 2048
#define D1 128
#define D2 64
#define D3 20
#define NE (RR*EE)  // 500000 edges total

using short8  = __attribute__((ext_vector_type(8))) short;
using float4e = __attribute__((ext_vector_type(4))) float;

__device__ __forceinline__ unsigned short f2bf(float f) {
  unsigned int u = __float_as_uint(f);
  unsigned int r = u + 0x7fffu + ((u >> 16) & 1u);   // RNE
  return (unsigned short)(r >> 16);
}
__device__ __forceinline__ float bf2f(unsigned short u) {
  return __uint_as_float(((unsigned int)u) << 16);
}
__device__ __forceinline__ unsigned int pk2(float lo, float hi) {
  return ((unsigned int)f2bf(hi) << 16) | (unsigned int)f2bf(lo);
}

// bf16x8 MFMA on uint4-typed fragments
__device__ __forceinline__ float4e bmm(uint4 a, uint4 b, float4e c) {
  return __builtin_amdgcn_mfma_f32_16x16x32_bf16(
      __builtin_bit_cast(short8, a), __builtin_bit_cast(short8, b), c, 0, 0, 0);
}

// ---------------------------------------------------------------------------
// fused prep: deg histogram + all three weight->bf16 fragment-layout packs
// frag element (for a 16-col tile nt): k = c*32 + (lane>>4)*8 + j,
//                                      n = nt*16 + (lane&15)
// ---------------------------------------------------------------------------
#define W0_SZ 262144   // drug_w frags: c 0..63, nt 0..7
#define W1_SZ 73728    // Wc1 frags:    c 0..35, nt 0..3
#define W2_SZ 18432    // Wc2 frags:    c 0..17, nt 0..1
__global__ void prep_kernel(const int* __restrict__ ei, int* __restrict__ deg,
                            const float* __restrict__ drug_w,
                            unsigned short* __restrict__ Bfw,
                            const float* __restrict__ root1,
                            const float* __restrict__ basis1,
                            unsigned short* __restrict__ Wf1,
                            const float* __restrict__ root2,
                            const float* __restrict__ basis2,
                            unsigned short* __restrict__ Wf2) {
  int gid = blockIdx.x * 256 + threadIdx.x;
  if (gid < NE) {
    int r = gid / EE, e = gid - r * EE;
    int d = ei[r * 2 * EE + EE + e];
    atomicAdd(&deg[r * NN + d], 1);
    return;
  }
  gid -= NE;
  if (gid < W0_SZ) {
    int j = gid & 7, lane = (gid >> 3) & 63, rest = gid >> 9;
    int nt = rest & 7, c = rest >> 3;
    int k = c * 32 + (lane >> 4) * 8 + j;
    int n = nt * 16 + (lane & 15);
    Bfw[gid] = f2bf(drug_w[(size_t)k * 128 + n]);
    return;
  }
  gid -= W0_SZ;
  if (gid < W1_SZ) {
    int j = gid & 7, lane = (gid >> 3) & 63, rest = gid >> 9;
    int nt = rest & 3, c = rest >> 2;
    int k = c * 32 + (lane >> 4) * 8 + j;
    int o = nt * 16 + (lane & 15);
    float v = (k < 128) ? root1[k * 64 + o] : basis1[(k - 128) * 64 + o];
    Wf1[gid] = f2bf(v);
    return;
  }
  gid -= W1_SZ;
  if (gid < W2_SZ) {
    int j = gid & 7, lane = (gid >> 3) & 63, rest = gid >> 9;
    int nt = rest & 1, c = rest >> 1;
    int k = c * 32 + (lane >> 4) * 8 + j;
    int cc = nt * 16 + (lane & 15);
    float v = 0.f;
    if (cc < 20) v = (k < 64) ? root2[k * 20 + cc] : basis2[(k - 64) * 20 + cc];
    Wf2[gid] = f2bf(v);
  }
}

__global__ void cnt_kernel(const int* __restrict__ deg, int* __restrict__ cnt) {
  int n = blockIdx.x * 256 + threadIdx.x;
  if (n >= NN) return;
  int s = 0;
  for (int r = 0; r < RR; r++) s += deg[r * NN + n];
  cnt[n] = s;
}

__global__ __launch_bounds__(1024) void scan_kernel(const int* __restrict__ cnt,
                                                    int* __restrict__ off,
                                                    int* __restrict__ cur) {
  __shared__ int wsum[16];
  __shared__ int carry_s;
  const int tid = threadIdx.x;
  const int wv = tid >> 6, lane = tid & 63;
  if (tid == 0) carry_s = 0;
  __syncthreads();
  for (int base = 0; base < NN; base += 1024) {
    int i = base + tid;
    int v = (i < NN) ? cnt[i] : 0;
    int s = v;
#pragma unroll
    for (int d = 1; d < 64; d <<= 1) {
      int t = __shfl_up(s, d, 64);
      if (lane >= d) s += t;
    }
    if (lane == 63) wsum[wv] = s;
    __syncthreads();
    if (wv == 0) {
      int w = (lane < 16) ? wsum[lane] : 0;
#pragma unroll
      for (int d = 1; d < 16; d <<= 1) {
        int t = __shfl_up(w, d, 64);
        if (lane >= d) w += t;
      }
      if (lane < 16) wsum[lane] = w;
    }
    __syncthreads();
    int excl = carry_s + (wv > 0 ? wsum[wv - 1] : 0) + s - v;
    if (i < NN) { off[i] = excl; cur[i] = excl; }
    __syncthreads();
    if (tid == 1023) carry_s += wsum[15];
    __syncthreads();
  }
  if (tid == 0) off[NN] = carry_s;
}

// rec = (r<<14)|src, esc = 1/max(deg,1)
__global__ void scatter_kernel(const int* __restrict__ ei,
                               const int* __restrict__ deg,
                               int* __restrict__ cur, int* __restrict__ rec,
                               float* __restrict__ esc) {
  int gid = blockIdx.x * 256 + threadIdx.x;
  if (gid >= NE) return;
  int r = gid / EE, e = gid - r * EE;
  int s = ei[r * 2 * EE + e];
  int d = ei[r * 2 * EE + EE + e];
  int p = atomicAdd(&cur[d], 1);
  rec[p] = (r << 14) | s;
  esc[p] = 1.0f / fmaxf((float)deg[r * NN + d], 1.0f);
}

// ---------------------------------------------------------------------------
// gemm0_v4: xb = bf16(x_drug @ drug_w)
// M=64 per block (157 blocks), N=128, 4 waves (wave nw: cols nw*32..+32,
// all 64 rows). A: coalesced fp32 loads -> bf16 -> XOR-swizzled LDS
// [2][64][128], 2 K-tiles ahead in regs. B: direct frag-layout loads
// (L2-resident), 1 tile ahead. 16 K-tiles of 128; 2 barriers / 2 tiles.
// ---------------------------------------------------------------------------
__global__ __launch_bounds__(256) void gemm0_v4(
    const float* __restrict__ A, const unsigned short* __restrict__ Bfw,
    unsigned short* __restrict__ xb) {
  __shared__ unsigned short As[2][64 * 128];
  const int tid = threadIdx.x;
  const int nw = tid >> 6, lane = tid & 63;
  const int lrow = lane & 15, quad = lane >> 4;
  const int m0 = blockIdx.x * 64;

  // staging: thread covers rows rb+8j (j=0..7), 1 float4 per row (li*16B)
  const int rb = tid >> 5, li = tid & 31;
  int rg[8], wo[8];
#pragma unroll
  for (int j = 0; j < 8; j++) {
    int r = rb + 8 * j;
    int g = m0 + r;
    rg[j] = g < NN ? g : NN - 1;
    wo[j] = r * 128 + (((li >> 1) ^ (r & 15)) & 15) * 8 + (li & 1) * 4;
  }

  const uint4* Bq = (const uint4*)Bfw;
  float4 rAe[8], rAo[8];
  uint4 B0[8], B1[8];
  float4e acc[4][2];
#pragma unroll
  for (int mt = 0; mt < 4; mt++)
#pragma unroll
    for (int i = 0; i < 2; i++) {
      acc[mt][i][0] = 0.f; acc[mt][i][1] = 0.f;
      acc[mt][i][2] = 0.f; acc[mt][i][3] = 0.f;
    }

#define LDA(ra, t)                                                   \
  { int tc = (t) > 15 ? 15 : (t);                                    \
    _Pragma("unroll")                                                \
    for (int j = 0; j < 8; j++)                                      \
      ra[j] = *(const float4*)(A + (size_t)rg[j] * D0 + tc * 128 + li * 4); }
#define LDB(B, t)                                                    \
  { int tc = (t) > 15 ? 15 : (t);                                    \
    _Pragma("unroll")                                                \
    for (int kk = 0; kk < 4; kk++) {                                 \
      B[2 * kk]     = Bq[((tc * 4 + kk) * 8 + 2 * nw) * 64 + lane];  \
      B[2 * kk + 1] = Bq[((tc * 4 + kk) * 8 + 2 * nw + 1) * 64 + lane]; } }
#define STA(buf, ra)                                                 \
  { _Pragma("unroll")                                                \
    for (int j = 0; j < 8; j++) {                                    \
      uint2 u; u.x = pk2(ra[j].x, ra[j].y); u.y = pk2(ra[j].z, ra[j].w); \
      *(uint2*)&As[buf][wo[j]] = u; } }
#define CMP(buf, B)                                                  \
  { _Pragma("unroll")                                                \
    for (int kk = 0; kk < 4; kk++) {                                 \
      _Pragma("unroll")                                              \
      for (int mt = 0; mt < 4; mt++) {                               \
        uint4 af = *(const uint4*)&As[buf][(mt * 16 + lrow) * 128 +  \
                                           (((kk * 4 + quad) ^ lrow) & 15) * 8]; \
        acc[mt][0] = bmm(af, B[2 * kk], acc[mt][0]);                 \
        acc[mt][1] = bmm(af, B[2 * kk + 1], acc[mt][1]); } } }

  LDA(rAe, 0); LDB(B0, 0);
  LDA(rAo, 1);
  STA(0, rAe);
  LDB(B1, 1);
  LDA(rAe, 2);
  __syncthreads();

  for (int t = 0; t < 16; t += 2) {
    STA(1, rAo);
    LDA(rAo, t + 3);
    CMP(0, B0);
    LDB(B0, t + 2);
    __syncthreads();
    STA(0, rAe);
    LDA(rAe, t + 4);
    CMP(1, B1);
    LDB(B1, t + 3);
    __syncthreads();
  }
#undef LDA
#undef LDB
#undef STA
#undef CMP

  const int c0 = nw * 32 + lrow;
#pragma unroll
  for (int mt = 0; mt < 4; mt++) {
#pragma unroll
    for (int j = 0; j < 4; j++) {
      int r = m0 + mt * 16 + quad * 4 + j;
      if (r < NN) {
        xb[(size_t)r * D1 + c0]      = f2bf(acc[mt][0][j]);
        xb[(size_t)r * D1 + c0 + 16] = f2bf(acc[mt][1][j]);
      }
    }
  }
}

// ---------------------------------------------------------------------------
// agg1e: A1b[n, b*128+i] = bf16( sum_{e->n} esc_e*comp1[r_e,b]*x[src_e,i] )
// one wave per node; lane holds 2 of 128 channels; sc*x factored out
// ---------------------------------------------------------------------------
__global__ __launch_bounds__(256) void agg1e_kernel(
    const unsigned short* __restrict__ xb, const int* __restrict__ off,
    const int* __restrict__ rec, const float* __restrict__ esc,
    const float* __restrict__ comp, unsigned short* __restrict__ A1b) {
  __shared__ float s_comp[RR * 8];
  const int tid = threadIdx.x;
  for (int i = tid; i < RR * 8; i += 256) s_comp[i] = comp[i];
  __syncthreads();
  const int wv = tid >> 6, lane = tid & 63;
  const int n = blockIdx.x * 4 + wv;
  if (n >= NN) return;
  float acc[8][2];
#pragma unroll
  for (int b = 0; b < 8; b++) { acc[b][0] = 0.f; acc[b][1] = 0.f; }
  const int beg = off[n], end = off[n + 1];
  int idx = beg;
  for (; idx + 3 < end; idx += 4) {
    int rc[4]; float sc[4]; unsigned int xv[4];
#pragma unroll
    for (int u = 0; u < 4; u++) {
      rc[u] = rec[idx + u];
      sc[u] = esc[idx + u];
    }
#pragma unroll
    for (int u = 0; u < 4; u++)
      xv[u] = *(const unsigned int*)&xb[(size_t)(rc[u] & 16383) * D1 + lane * 2];
#pragma unroll
    for (int u = 0; u < 4; u++) {
      const float* cb = &s_comp[(rc[u] >> 14) * 8];
      float sx0 = sc[u] * __uint_as_float((xv[u] & 0xffffu) << 16);
      float sx1 = sc[u] * __uint_as_float(xv[u] & 0xffff0000u);
#pragma unroll
      for (int b = 0; b < 8; b++) {
        acc[b][0] += cb[b] * sx0;
        acc[b][1] += cb[b] * sx1;
      }
    }
  }
  for (; idx < end; idx++) {
    int rc = rec[idx];
    float sc = esc[idx];
    unsigned int xv = *(const unsigned int*)&xb[(size_t)(rc & 16383) * D1 + lane * 2];
    const float* cb = &s_comp[(rc >> 14) * 8];
    float sx0 = sc * __uint_as_float((xv & 0xffffu) << 16);
    float sx1 = sc * __uint_as_float(xv & 0xffff0000u);
#pragma unroll
    for (int b = 0; b < 8; b++) {
      acc[b][0] += cb[b] * sx0;
      acc[b][1] += cb[b] * sx1;
    }
  }
#pragma unroll
  for (int b = 0; b < 8; b++) {
    ushort2 o; o.x = f2bf(acc[b][0]); o.y = f2bf(acc[b][1]);
    *(ushort2*)&A1b[(size_t)n * 1024 + b * 128 + lane * 2] = o;
  }
}

// ---------------------------------------------------------------------------
// agg2e: sc*h factored out
// ---------------------------------------------------------------------------
__global__ __launch_bounds__(256) void agg2e_kernel(
    const unsigned short* __restrict__ hb, const int* __restrict__ off,
    const int* __restrict__ rec, const float* __restrict__ esc,
    const float* __restrict__ comp, unsigned short* __restrict__ A2b) {
  __shared__ float s_comp[RR * 8];
  const int tid = threadIdx.x;
  for (int i = tid; i < RR * 8; i += 256) s_comp[i] = comp[i];
  __syncthreads();
  const int wv = tid >> 6, lane = tid & 63;
  const int n = blockIdx.x * 4 + wv;
  if (n >= NN) return;
  float acc[8];
#pragma unroll
  for (int b = 0; b < 8; b++) acc[b] = 0.f;
  const int beg = off[n], end = off[n + 1];
  int idx = beg;
  for (; idx + 3 < end; idx += 4) {
    int rc[4]; float sc[4]; float hv[4];
#pragma unroll
    for (int u = 0; u < 4; u++) {
      rc[u] = rec[idx + u];
      sc[u] = esc[idx + u];
    }
#pragma unroll
    for (int u = 0; u < 4; u++)
      hv[u] = bf2f(hb[(size_t)(rc[u] & 16383) * D2 + lane]);
#pragma unroll
    for (int u = 0; u < 4; u++) {
      const float* cb = &s_comp[(rc[u] >> 14) * 8];
      float sh = sc[u] * hv[u];
#pragma unroll
      for (int b = 0; b < 8; b++) acc[b] += cb[b] * sh;
    }
  }
  for (; idx < end; idx++) {
    int rc = rec[idx];
    float sc = esc[idx];
    float hv = bf2f(hb[(size_t)(rc & 16383) * D2 + lane]);
    const float* cb = &s_comp[(rc >> 14) * 8];
    float sh = sc * hv;
#pragma unroll
    for (int b = 0; b < 8; b++) acc[b] += cb[b] * sh;
  }
#pragma unroll
  for (int b = 0; b < 8; b++)
    A2b[(size_t)n * 512 + b * 64 + lane] = f2bf(acc[b]);
}

// ---------------------------------------------------------------------------
// hlayer_v4: hb = bf16(relu([xb|A1b](K=1152) @ Wc1 + bias1))
// M=32 (313 blocks), N=64, 4 waves (wave: mtile wv>>1, ntiles (wv&1)*2..+2).
// A staged coalesced bf16 -> swizzled LDS; 9 K-tiles of 128
// (tile 0 = xb rows, tiles 1..8 = A1b chunks). B direct frag-layout.
// ---------------------------------------------------------------------------
__global__ __launch_bounds__(256) void hlayer_v4(
    const unsigned short* __restrict__ xb, const unsigned short* __restrict__ A1b,
    const unsigned short* __restrict__ Wf, const float* __restrict__ bias1,
    unsigned short* __restrict__ hb) {
  __shared__ unsigned short Hs[2][32 * 128];
  const int tid = threadIdx.x;
  const int wv = tid >> 6, lane = tid & 63;
  const int lrow = lane & 15, quad = lane >> 4;
  const int m0 = blockIdx.x * 32;
  const int mt = wv >> 1, nb = (wv & 1) * 2;

  // staging: 512 uint4 slots (32 rows x 16); thread covers idx = tid, tid+256
  int rgr[2], su4[2], sph[2];
#pragma unroll
  for (int p = 0; p < 2; p++) {
    int idx = tid + p * 256;
    int r = idx >> 4, u = idx & 15;
    int g = m0 + r;
    rgr[p] = g < NN ? g : NN - 1;
    su4[p] = u;
    sph[p] = r * 128 + ((u ^ (r & 15)) & 15) * 8;
  }

  const uint4* Bq = (const uint4*)Wf;
  uint4 rAe[2], rAo[2];
  uint4 B0[8], B1[8];
  float4e acc[2];
#pragma unroll
  for (int i = 0; i < 2; i++) {
    acc[i][0] = 0.f; acc[i][1] = 0.f; acc[i][2] = 0.f; acc[i][3] = 0.f;
  }

#define H_LDA(ra, t)                                                       \
  { int tc = (t) > 8 ? 8 : (t);                                            \
    _Pragma("unroll")                                                      \
    for (int p = 0; p < 2; p++) {                                          \
      const unsigned short* sp = (tc == 0)                                 \
          ? (xb + (size_t)rgr[p] * D1 + su4[p] * 8)                        \
          : (A1b + (size_t)rgr[p] * 1024 + (tc - 1) * 128 + su4[p] * 8);   \
      ra[p] = *(const uint4*)sp; } }
#define H_LDB(B, t)                                                        \
  { int tc = (t) > 8 ? 8 : (t);                                            \
    _Pragma("unroll")                                                      \
    for (int kk = 0; kk < 4; kk++) {                                       \
      int c = tc * 4 + kk;                                                 \
      B[2 * kk]     = Bq[(c * 4 + nb) * 64 + lane];                        \
      B[2 * kk + 1] = Bq[(c * 4 + nb + 1) * 64 + lane]; } }
#define H_STA(buf, ra)                                                     \
  { _Pragma("unroll")                                                      \
    for (int p = 0; p < 2; p++) *(uint4*)&Hs[buf][sph[p]] = ra[p]; }
#define H_CMP(buf, B)                                                      \
  { _Pragma("unroll")                                                      \
    for (int kk = 0; kk < 4; kk++) {                                       \
      uint4 af = *(const uint4*)&Hs[buf][(mt * 16 + lrow) * 128 +          \
                                         (((kk * 4 + quad) ^ lrow) & 15) * 8]; \
      acc[0] = bmm(af, B[2 * kk], acc[0]);                                 \
      acc[1] = bmm(af, B[2 * kk + 1], acc[1]); } }

  H_LDA(rAe, 0); H_LDB(B0, 0);
  H_LDA(rAo, 1);
  H_STA(0, rAe);
  H_LDB(B1, 1);
  H_LDA(rAe, 2);
  __syncthreads();

  for (int t = 0; t < 8; t += 2) {
    H_STA(1, rAo);
    H_LDA(rAo, t + 3);
    H_CMP(0, B0);
    H_LDB(B0, t + 2);
    __syncthreads();
    H_STA(0, rAe);
    H_LDA(rAe, t + 4);
    H_CMP(1, B1);
    H_LDB(B1, t + 3);
    __syncthreads();
  }
  H_CMP(0, B0);                                   // tile 8
#undef H_LDA
#undef H_LDB
#undef H_STA
#undef H_CMP

#pragma unroll
  for (int ntl = 0; ntl < 2; ntl++) {
    int col = (nb + ntl) * 16 + lrow;
    float bv = bias1[col];
#pragma unroll
    for (int j = 0; j < 4; j++) {
      int r = m0 + mt * 16 + quad * 4 + j;
      if (r < NN)
        hb[(size_t)r * D2 + col] = f2bf(fmaxf(acc[ntl][j] + bv, 0.f));
    }
  }
}

// ---------------------------------------------------------------------------
// out_v4: out = [hb|A2b](K=576) @ Wc2 + bias2
// M=32 (313 blocks), N=32, 2 waves (wave wv: mtile wv, both ntiles).
// 9 K-tiles of 64 (tile 0 = hb, tiles 1..8 = A2b chunks).
// ---------------------------------------------------------------------------
__global__ __launch_bounds__(128) void out_v4(
    const unsigned short* __restrict__ hb, const unsigned short* __restrict__ A2b,
    const unsigned short* __restrict__ Wf, const float* __restrict__ bias2,
    float* __restrict__ out) {
  __shared__ unsigned short Os[2][32 * 64];
  const int tid = threadIdx.x;
  const int wv = tid >> 6, lane = tid & 63;
  const int lrow = lane & 15, quad = lane >> 4;
  const int m0 = blockIdx.x * 32;

  // staging: 256 uint4 slots (32 rows x 8); thread covers idx = tid, tid+128
  int rgr[2], su4[2], sph[2];
#pragma unroll
  for (int p = 0; p < 2; p++) {
    int idx = tid + p * 128;
    int r = idx >> 3, u = idx & 7;
    int g = m0 + r;
    rgr[p] = g < NN ? g : NN - 1;
    su4[p] = u;
    sph[p] = r * 64 + ((u ^ (r & 7)) & 7) * 8;
  }

  const uint4* Bq = (const uint4*)Wf;
  uint4 rAe[2], rAo[2];
  uint4 B0[4], B1[4];
  float4e acc[2];
#pragma unroll
  for (int i = 0; i < 2; i++) {
    acc[i][0] = 0.f; acc[i][1] = 0.f; acc[i][2] = 0.f; acc[i][3] = 0.f;
  }

#define O_LDA(ra, t)                                                       \
  { int tc = (t) > 8 ? 8 : (t);                                            \
    _Pragma("unroll")                                                      \
    for (int p = 0; p < 2; p++) {                                          \
      const unsigned short* sp = (tc == 0)                                 \
          ? (hb + (size_t)rgr[p] * D2 + su4[p] * 8)                        \
          : (A2b + (size_t)rgr[p] * 512 + (tc - 1) * 64 + su4[p] * 8);     \
      ra[p] = *(const uint4*)sp; } }
#define O_LDB(B, t)                                                        \
  { int tc = (t) > 8 ? 8 : (t);                                            \
    _Pragma("unroll")                                                      \
    for (int kk = 0; kk < 2; kk++) {                                       \
      int c = tc * 2 + kk;                                                 \
      B[2 * kk]     = Bq[(c * 2) * 64 + lane];                             \
      B[2 * kk + 1] = Bq[(c * 2 + 1) * 64 + lane]; } }
#define O_STA(buf, ra)                                                     \
  { _Pragma("unroll")                                                      \
    for (int p = 0; p < 2; p++) *(uint4*)&Os[buf][sph[p]] = ra[p]; }
#define O_CMP(buf, B)                                                      \
  { _Pragma("unroll")                                                      \
    for (int kk = 0; kk < 2; kk++) {                                       \
      uint4 af = *(const uint4*)&Os[buf][(wv * 16 + lrow) * 64 +           \
                                         (((kk * 4 + quad) ^ lrow) & 7) * 8]; \
      acc[0] = bmm(af, B[2 * kk], acc[0]);                                 \
      acc[1] = bmm(af, B[2 * kk + 1], acc[1]); } }

  O_LDA(rAe, 0); O_LDB(B0, 0);
  O_LDA(rAo, 1);
  O_STA(0, rAe);
  O_LDB(B1, 1);
  O_LDA(rAe, 2);
  __syncthreads();

  for (int t = 0; t < 8; t += 2) {
    O_STA(1, rAo);
    O_LDA(rAo, t + 3);
    O_CMP(0, B0);
    O_LDB(B0, t + 2);
    __syncthreads();
    O_STA(0, rAe);
    O_LDA(rAe, t + 4);
    O_CMP(1, B1);
    O_LDB(B1, t + 3);
    __syncthreads();
  }
  O_CMP(0, B0);                                   // tile 8
#undef O_LDA
#undef O_LDB
#undef O_STA
#undef O_CMP

#pragma unroll
  for (int ntl = 0; ntl < 2; ntl++) {
    int col = ntl * 16 + lrow;
    if (col < D3) {
      float bv = bias2[col];
#pragma unroll
      for (int j = 0; j < 4; j++) {
        int r = m0 + wv * 16 + quad * 4 + j;
        if (r < NN)
          out[(size_t)r * D3 + col] = acc[ntl][j] + bv;
      }
    }
  }
}

// ---------------------------------------------------------------------------
extern "C" void kernel_launch(void* const* d_in, const int* in_sizes, int n_in,
                              void* d_out, int out_size, void* d_ws,
                              size_t ws_size, hipStream_t stream) {
  const float* x_drug = (const float*)d_in[0];
  const float* drug_w = (const float*)d_in[1];
  const int*   ei     = (const int*)d_in[2];
  const float* basis1 = (const float*)d_in[3];
  const float* comp1  = (const float*)d_in[4];
  const float* root1  = (const float*)d_in[5];
  const float* bias1  = (const float*)d_in[6];
  const float* basis2 = (const float*)d_in[7];
  const float* comp2  = (const float*)d_in[8];
  const float* root2  = (const float*)d_in[9];
  const float* bias2  = (const float*)d_in[10];
  float* out = (float*)d_out;

  float* ws = (float*)d_ws;
  int*   deg  = (int*)ws;                          // 1,000,000
  int*   cnt  = deg + 1000000;                     // 10,016
  int*   off  = cnt + 10016;                       // 10,016
  int*   cur  = off + 10016;                       // 10,016
  int*   rec  = cur + 10016;                       // 500,000
  float* esc  = (float*)(rec + 500000);            // 500,000
  unsigned short* xb   = (unsigned short*)(esc + 500000);          // 640,000 f
  unsigned short* hb   = (unsigned short*)((float*)xb + 640000);   // 320,000 f
  unsigned short* Bfw  = (unsigned short*)((float*)hb + 320000);   // 131,072 f
  unsigned short* Wf1  = (unsigned short*)((float*)Bfw + 131072);  // 36,864 f
  unsigned short* Wf2  = (unsigned short*)((float*)Wf1 + 36864);   // 9,216 f
  float* R1 = (float*)Wf2 + 9216;                  // aggregation buffers
  unsigned short* A1b = (unsigned short*)R1;       // 10,000 x 1024 bf16
  unsigned short* A2b = (unsigned short*)R1;       // aliases A1b (after hlayer)

  hipMemsetAsync(deg, 0, (size_t)1000000 * 4, stream);

  // CSR build + weight prep (fused first pass)
  prep_kernel<<<(NE + W0_SZ + W1_SZ + W2_SZ + 255) / 256, 256, 0, stream>>>(
      ei, deg, drug_w, Bfw, root1, basis1, Wf1, root2, basis2, Wf2);
  cnt_kernel<<<(NN + 255) / 256, 256, 0, stream>>>(deg, cnt);
  scan_kernel<<<1, 1024, 0, stream>>>(cnt, off, cur);
  scatter_kernel<<<(NE + 255) / 256, 256, 0, stream>>>(ei, deg, cur, rec, esc);

  // x = x_drug @ drug_w
  gemm0_v4<<<(NN + 63) / 64, 256, 0, stream>>>(x_drug, Bfw, xb);

  // layer 1
  agg1e_kernel<<<(NN + 3) / 4, 256, 0, stream>>>(xb, off, rec, esc, comp1, A1b);
  hlayer_v4<<<(NN + 31) / 32, 256, 0, stream>>>(xb, A1b, Wf1, bias1, hb);

  // layer 2
  agg2e_kernel<<<(NN + 3) / 4, 256, 0, stream>>>(hb, off, rec, esc, comp2, A2b);
  out_v4<<<(NN + 31) / 32, 128, 0, stream>>>(hb, A2b, Wf2, bias2, out);
}